// Round 9
// baseline (370.137 us; speedup 1.0000x reference)
//
#include <hip/hip_runtime.h>

#define N_ATOMS 65536
#define AF      133
#define BT      147
#define HID     256
#define NNB     6
#define NM      2048

#define KI   160        // atom(133) padded
#define KB   32         // bond(14) padded
#define KP   256        // msg-side GEMMs (exact)
// LDS strides (elements)
#define LSI  168
#define LSB  40
#define LSP  268        // 268 (not 264): quad stride 536 dw % 32 = 24 ->
                        // epi quads hit distinct bank octets (was 4-way)

#define BM   64         // rows per block
#define THR  1024       // 16 waves = 8 col-waves x 2 row-groups

typedef __attribute__((ext_vector_type(8))) short short8;
typedef __attribute__((ext_vector_type(4))) float f32x4;

__device__ __forceinline__ unsigned short f2bf(float f) {
    unsigned u = __builtin_bit_cast(unsigned, f);
    u += 0x7fffu + ((u >> 16) & 1u);
    return (unsigned short)(u >> 16);
}
__device__ __forceinline__ float bf2f(unsigned short s) {
    unsigned u = ((unsigned)s) << 16;
    return __builtin_bit_cast(float, u);
}

// ---------------------------------------------------------------------------
// Fragment-order index for a [256 x K] W^T (bf16) in MFMA B-fragment order.
// ---------------------------------------------------------------------------
__device__ __forceinline__ size_t fidx(int K, int n, int k) {
    return ((size_t)(((n >> 4) * (K >> 5) + (k >> 5)) * 64
                     + (((k >> 3) & 3) << 4) + (n & 15)) << 3) + (k & 7);
}

// ---------------------------------------------------------------------------
// k_prep_bond: weight transposes -> FRAGMENT ORDER (bf16) + b_ih + bondsum.
// (standalone bond gather: folding into k_inp failed in R6 — VMEM retires
//  in order, slow gathers poison later vmcnt waits.)
// ---------------------------------------------------------------------------
__global__ __launch_bounds__(256) void k_prep_bond(const float* __restrict__ Wi,
                                                   const float* __restrict__ Wh,
                                                   const float* __restrict__ Wo,
                                                   const float* __restrict__ bi,
                                                   const float* __restrict__ bh,
                                                   const float* __restrict__ f_bonds,
                                                   const int* __restrict__ a2b,
                                                   unsigned short* __restrict__ Wi_f,
                                                   unsigned short* __restrict__ Wb_f,
                                                   unsigned short* __restrict__ Whm_f,
                                                   unsigned short* __restrict__ Woa_f,
                                                   unsigned short* __restrict__ Wom_f,
                                                   unsigned short* __restrict__ bondsum,
                                                   float* __restrict__ b_ih) {
    if (blockIdx.x < 256) {
        const int n = blockIdx.x;
        if (n == 0) b_ih[threadIdx.x] = bi[threadIdx.x] + bh[threadIdx.x];
        for (int k = threadIdx.x; k < KI; k += 256) {
            Wi_f[fidx(KI, n, k)]  = f2bf(k < AF ? Wi[k * HID + n] : 0.f);
            Woa_f[fidx(KI, n, k)] = f2bf(k < AF ? Wo[k * HID + n] : 0.f);
        }
        for (int k = threadIdx.x; k < KB; k += 256)
            Wb_f[fidx(KB, n, k)] = f2bf(k < 14 ? Wh[(HID + k) * HID + n] : 0.f);
        for (int k = threadIdx.x; k < KP; k += 256) {
            Whm_f[fidx(KP, n, k)] = f2bf(Wh[k * HID + n]);
            Wom_f[fidx(KP, n, k)] = f2bf(Wo[(AF + k) * HID + n]);
        }
    } else {
        const int id   = (blockIdx.x - 256) * 256 + threadIdx.x;
        const int atom = id >> 4;
        const int c    = id & 15;
        float s = 0.f;
        if (c < 14) {
            const int* nb = &a2b[atom * NNB];
#pragma unroll
            for (int t = 0; t < NNB; ++t)
                s += f_bonds[(size_t)nb[t] * BT + (BT - 14) + c];
        }
        bondsum[atom * 32 + c]      = f2bf(s);
        bondsum[atom * 32 + 16 + c] = 0;
    }
}

// ---------------------------------------------------------------------------
// MFMA core with B-panel register prefetch. As pre-offset to the wave's
// 32-row group. cw = col-wave (0..7) owning cols cw*32 .. cw*32+31.
// ---------------------------------------------------------------------------
template<int K, int LS>
__device__ __forceinline__ void mfma_core_pf(const unsigned short* __restrict__ As,
                                             const unsigned short* __restrict__ Wt,
                                             f32x4 (&acc)[2][2], int cw, int lane) {
    constexpr int NK = K >> 5;
    const int lm = lane & 15, quad = lane >> 4;
    const short8* __restrict__ Wf = (const short8*)Wt;
    short8 bf[2][NK];
#pragma unroll
    for (int ks = 0; ks < NK; ++ks)
#pragma unroll
        for (int ct = 0; ct < 2; ++ct)
            bf[ct][ks] = Wf[(size_t)((cw * 2 + ct) * NK + ks) * 64 + lane];
#pragma unroll
    for (int ks = 0; ks < NK; ++ks) {
        short8 af[2];
#pragma unroll
        for (int rt = 0; rt < 2; ++rt)
            af[rt] = *(const short8*)&As[(rt * 16 + lm) * LS + ks * 32 + quad * 8];
#pragma unroll
        for (int rt = 0; rt < 2; ++rt)
#pragma unroll
            for (int ct = 0; ct < 2; ++ct)
                acc[rt][ct] = __builtin_amdgcn_mfma_f32_16x16x32_bf16(af[rt], bf[ct][ks], acc[rt][ct], 0, 0, 0);
    }
}

// C-layout acc -> bf16 tile in LDS (E pre-offset to wave's 32 rows)
__device__ __forceinline__ void epi_to_lds(f32x4 (&acc)[2][2],
                                           const float* __restrict__ bias,
                                           bool relu_,
                                           unsigned short* __restrict__ E,
                                           int cw, int lane) {
    const int lm = lane & 15, quad = lane >> 4;
#pragma unroll
    for (int ct = 0; ct < 2; ++ct) {
        int col = cw * 32 + ct * 16 + lm;
        float bv = bias ? bias[col] : 0.f;
#pragma unroll
        for (int rt = 0; rt < 2; ++rt)
#pragma unroll
            for (int i = 0; i < 4; ++i) {
                float v = acc[rt][ct][i] + bv;
                if (relu_) v = fmaxf(v, 0.f);
                E[(rt * 16 + quad * 4 + i) * LSP + col] = f2bf(v);
            }
    }
}

// coalesced 16B row-major store of a BM x 256 LDS tile, NT threads
template<int NT>
__device__ __forceinline__ void store_tile(unsigned short* __restrict__ dst, int base,
                                           const unsigned short* __restrict__ E, int tid) {
#pragma unroll
    for (int k = 0; k < BM * HID / (8 * NT); ++k) {
        int j = k * NT + tid;
        int r = j >> 5, g = j & 31;
        *(short8*)&dst[(size_t)(base + r) * HID + g * 8] = *(const short8*)&E[r * LSP + g * 8];
    }
}

// ---------------------------------------------------------------------------
// k_inp: BM=64, 1024 thr (16 waves = 8 col x 2 row-groups), 5 barriers.
// Same per-wave shape/regs as R8's (512,8) -> still 8 waves/SIMD (2 blocks
// of 72 KB LDS = 144 KB/CU), but per-block B-panel traffic HALVED
// (1024 blocks x 320 KB instead of 2048 x 320 KB through L1/L2).
// ---------------------------------------------------------------------------
__global__ __launch_bounds__(THR, 8) void k_inp(const float* __restrict__ atom,
                                                const unsigned short* __restrict__ bondsum,
                                                const unsigned short* __restrict__ Wi_f,
                                                const unsigned short* __restrict__ Wb_f,
                                                const unsigned short* __restrict__ Whm_f,
                                                const unsigned short* __restrict__ Woa_f,
                                                const float* __restrict__ bi,
                                                const float* __restrict__ b_ih,
                                                const float* __restrict__ bo,
                                                unsigned short* __restrict__ P0,
                                                unsigned short* __restrict__ inp2,
                                                unsigned short* __restrict__ aw) {
    // pool: X (BM*LSP: atomT then epi tile B) | work (BM*LSP) | bs (BM*LSB)
    __shared__ unsigned short pool[BM * LSP * 2 + BM * LSB];  // 73728 B
    unsigned short* X    = pool;
    unsigned short* work = pool + BM * LSP;
    unsigned short* bs   = pool + BM * LSP * 2;
    const int tid  = threadIdx.x;
    const int base = blockIdx.x * BM;

    for (int it = tid; it < BM * KI; it += THR) {
        int r = it / KI, c = it - r * KI;
        X[r * LSI + c] = f2bf(c < AF ? atom[(size_t)(base + r) * AF + c] : 0.f);
    }
    if (tid < BM * 4) {
        int r = tid >> 2, c = (tid & 3) * 8;
        *(short8*)&bs[r * LSB + c] = *(const short8*)&bondsum[(size_t)(base + r) * 32 + c];
    }
    __syncthreads();                                    // (1) staging visible

    const int lane = tid & 63, wave = tid >> 6;
    const int cw = wave & 7, rg = wave >> 3;            // col-wave, row-group
    f32x4 acc1[2][2] = {}, acc3[2][2] = {};
    mfma_core_pf<KI, LSI>(X + rg * 32 * LSI, Wi_f, acc1, cw, lane);   // inp
    mfma_core_pf<KI, LSI>(X + rg * 32 * LSI, Woa_f, acc3, cw, lane);  // aw
    __syncthreads();                                    // (2) atomT reads done

    epi_to_lds(acc3, bo, false, X + rg * 32 * LSP, cw, lane);
    epi_to_lds(acc1, bi, true, work + rg * 32 * LSP, cw, lane);   // mT
    __syncthreads();                                    // (3)

    store_tile<THR>(aw, base, X, tid);                  // overlaps MFMAs below
    f32x4 acc2[2][2] = {};
    mfma_core_pf<KP, LSP>(work + rg * 32 * LSP, Whm_f, acc2, cw, lane);
    mfma_core_pf<KB, LSB>(bs + rg * 32 * LSB, Wb_f, acc1, cw, lane);
    __syncthreads();                                    // (4) mT/X/bs reads done

    epi_to_lds(acc2, nullptr, false, X + rg * 32 * LSP, cw, lane);
    epi_to_lds(acc1, b_ih, false, work + rg * 32 * LSP, cw, lane);
    __syncthreads();                                    // (5)

    store_tile<THR>(P0, base, X, tid);
    store_tile<THR>(inp2, base, work, tid);
}

// ---------------------------------------------------------------------------
// k_it (fused gather+proj): BM=64, 1024 thr. nb_l LDS broadcast (proven).
//   m = relu(base_ + sum_t Pin[a2a[.,t]]);  Pout = m @ Wt
// B-panel traffic halved vs 32-row tiles; 8 waves/SIMD preserved (36 KB LDS).
// ---------------------------------------------------------------------------
__global__ __launch_bounds__(THR, 8) void k_it(const unsigned short* __restrict__ Pin,
                                               const unsigned short* __restrict__ base_,
                                               const int* __restrict__ a2a,
                                               const unsigned short* __restrict__ Wt,
                                               unsigned short* __restrict__ Pout) {
    __shared__ unsigned short mT[BM * LSP];
    __shared__ int nb_l[BM * NNB];
    const int tid  = threadIdx.x;
    const int base = blockIdx.x * BM;

    if (tid < BM * NNB) nb_l[tid] = a2a[base * NNB + tid];
    __syncthreads();

#pragma unroll
    for (int k = 0; k < BM * HID / (8 * THR); ++k) {
        int j = k * THR + tid;
        int r = j >> 5, g = j & 31;
        const int* nb = &nb_l[r * NNB];
        float s[8] = {};
#pragma unroll
        for (int t = 0; t < NNB; ++t) {
            short8 u = *(const short8*)&Pin[(size_t)nb[t] * HID + g * 8];
#pragma unroll
            for (int q = 0; q < 8; ++q) s[q] += bf2f((unsigned short)u[q]);
        }
        short8 b = *(const short8*)&base_[(size_t)(base + r) * HID + g * 8];
        short8 o;
#pragma unroll
        for (int q = 0; q < 8; ++q)
            o[q] = (short)f2bf(fmaxf(s[q] + bf2f((unsigned short)b[q]), 0.f));
        *(short8*)&mT[r * LSP + g * 8] = o;
    }
    __syncthreads();

    const int lane = tid & 63, wave = tid >> 6;
    const int cw = wave & 7, rg = wave >> 3;
    f32x4 acc[2][2] = {};
    mfma_core_pf<KP, LSP>(mT + rg * 32 * LSP, Wt, acc, cw, lane);
    __syncthreads();
    epi_to_lds(acc, nullptr, false, mT + rg * 32 * LSP, cw, lane);
    __syncthreads();
    store_tile<THR>(Pout, base, mT, tid);
}

// ---------------------------------------------------------------------------
// k_gseg (fused final gather + segment mean): one block per molecule.
// (256,8): 32 waves/CU; gather loop unroll 2.
// ---------------------------------------------------------------------------
__global__ __launch_bounds__(256, 8) void k_gseg(const unsigned short* __restrict__ P,
                                                 const unsigned short* __restrict__ aw,
                                                 const int* __restrict__ a2a,
                                                 const int* __restrict__ seg,
                                                 float* __restrict__ out) {
    const int m = blockIdx.x;
    __shared__ int lohi[2];
    __shared__ float red[8 * 256];   // 8 KB
    if (threadIdx.x == 0) {
        int lo = 0, hi = N_ATOMS;
        while (lo < hi) { int mid = (lo + hi) >> 1; if (seg[mid] < m) lo = mid + 1; else hi = mid; }
        lohi[0] = lo;
        int lo2 = lo, hi2 = N_ATOMS;
        while (lo2 < hi2) { int mid = (lo2 + hi2) >> 1; if (seg[mid] < m + 1) lo2 = mid + 1; else hi2 = mid; }
        lohi[1] = lo2;
    }
    __syncthreads();
    const int lo = lohi[0], hi = lohi[1];
    const int slot = threadIdx.x >> 5;    // 0..7 (row slot)
    const int cg   = threadIdx.x & 31;    // 0..31 (8-channel group)

    float s[8] = {};
#pragma unroll 2
    for (int i0 = lo; i0 < hi; i0 += 8) {
        int i = i0 + slot;
        if (i < hi) {
            const int* nb = &a2a[i * NNB];
            short8 a = *(const short8*)&aw[(size_t)i * HID + cg * 8];
            float v[8];
#pragma unroll
            for (int q = 0; q < 8; ++q) v[q] = bf2f((unsigned short)a[q]);
#pragma unroll
            for (int t = 0; t < NNB; ++t) {
                short8 u = *(const short8*)&P[(size_t)nb[t] * HID + cg * 8];
#pragma unroll
                for (int q = 0; q < 8; ++q) v[q] += bf2f((unsigned short)u[q]);
            }
#pragma unroll
            for (int q = 0; q < 8; ++q) s[q] += fmaxf(v[q], 0.f);
        }
    }
#pragma unroll
    for (int q = 0; q < 8; ++q) red[slot * 256 + cg * 8 + q] = s[q];
    __syncthreads();

    const int j = threadIdx.x;
    float tot = 0.f;
#pragma unroll
    for (int sl = 0; sl < 8; ++sl) tot += red[sl * 256 + j];
    const int cnt = hi - lo;
    out[m * HID + j] = (cnt > 0) ? (tot / (float)cnt) : 0.f;
}

// ---------------------------------------------------------------------------
extern "C" void kernel_launch(void* const* d_in, const int* in_sizes, int n_in,
                              void* d_out, int out_size, void* d_ws, size_t ws_size,
                              hipStream_t stream) {
    const float* atom    = (const float*)d_in[0];
    const float* f_bonds = (const float*)d_in[1];
    const int*   a2a     = (const int*)d_in[2];
    const int*   a2b     = (const int*)d_in[3];
    const int*   seg     = (const int*)d_in[4];
    const float* Wi      = (const float*)d_in[5];
    const float* bi      = (const float*)d_in[6];
    const float* Wh      = (const float*)d_in[7];
    const float* bh      = (const float*)d_in[8];
    const float* Wo      = (const float*)d_in[9];
    const float* bo      = (const float*)d_in[10];
    float* out = (float*)d_out;

    unsigned short* ws = (unsigned short*)d_ws;
    const size_t nh = (size_t)N_ATOMS * HID;
    unsigned short* Pa   = ws;               // 32 MB
    unsigned short* Pb   = Pa + nh;          // 32 MB
    unsigned short* inp2 = Pb + nh;          // 32 MB
    unsigned short* aw   = inp2 + nh;        // 32 MB
    unsigned short* bsum = aw + nh;          // 4 MB
    unsigned short* Wi_f  = bsum + (size_t)N_ATOMS * 32;
    unsigned short* Wb_f  = Wi_f + 256 * KI;
    unsigned short* Whm_f = Wb_f + 256 * KB;
    unsigned short* Woa_f = Whm_f + 256 * KP;
    unsigned short* Wom_f = Woa_f + 256 * KI;
    float*          b_ih  = (float*)(Wom_f + 256 * KP);

    dim3 blk256(256), blkT(THR);
    const int nbm = N_ATOMS / BM;   // 1024

    k_prep_bond<<<256 + N_ATOMS * 16 / 256, blk256, 0, stream>>>(
        Wi, Wh, Wo, bi, bh, f_bonds, a2b,
        Wi_f, Wb_f, Whm_f, Woa_f, Wom_f, bsum, b_ih);
    k_inp<<<nbm, blkT, 0, stream>>>(atom, bsum, Wi_f, Wb_f, Whm_f, Woa_f,
                                    bi, b_ih, bo, Pa, inp2, aw);

    k_it<<<nbm, blkT, 0, stream>>>(Pa, inp2, a2a, Whm_f, Pb);   // -> P1
    k_it<<<nbm, blkT, 0, stream>>>(Pb, inp2, a2a, Wom_f, Pa);   // -> P2
    k_gseg<<<NM, blk256, 0, stream>>>(Pa, aw, a2a, seg, out);
}

// Round 10
// 349.793 us; speedup vs baseline: 1.0582x; 1.0582x over previous
//
#include <hip/hip_runtime.h>

#define N_ATOMS 65536
#define AF      133
#define BT      147
#define HID     256
#define NNB     6
#define NM      2048

#define KI   160        // atom(133) padded
#define KB   32         // bond(14) padded
#define KP   256        // msg-side GEMMs (exact)
// LDS strides (elements)
#define LSI  168
#define LSB  40
#define LSP  268        // 268 (not 264): quad stride 536 dw % 32 = 24 ->
                        // epilogue quads hit distinct bank octets (R9-verified:
                        // SQ_LDS_BANK_CONFLICT -56%)

#define BM   32         // rows per block; 8 col-waves of 32 cols each (R8 best)

typedef __attribute__((ext_vector_type(8))) short short8;
typedef __attribute__((ext_vector_type(4))) float f32x4;

__device__ __forceinline__ unsigned short f2bf(float f) {
    unsigned u = __builtin_bit_cast(unsigned, f);
    u += 0x7fffu + ((u >> 16) & 1u);
    return (unsigned short)(u >> 16);
}
__device__ __forceinline__ float bf2f(unsigned short s) {
    unsigned u = ((unsigned)s) << 16;
    return __builtin_bit_cast(float, u);
}

// ---------------------------------------------------------------------------
// Fragment-order index for a [256 x K] W^T (bf16) in MFMA B-fragment order.
// ---------------------------------------------------------------------------
__device__ __forceinline__ size_t fidx(int K, int n, int k) {
    return ((size_t)(((n >> 4) * (K >> 5) + (k >> 5)) * 64
                     + (((k >> 3) & 3) << 4) + (n & 15)) << 3) + (k & 7);
}

// ---------------------------------------------------------------------------
// k_prep_bond: weight transposes -> FRAGMENT ORDER (bf16) + b_ih + bondsum.
// (standalone bond gather: folding into k_inp failed in R6 — VMEM retires
//  in order, slow gathers poison later vmcnt waits.)
// ---------------------------------------------------------------------------
__global__ __launch_bounds__(256) void k_prep_bond(const float* __restrict__ Wi,
                                                   const float* __restrict__ Wh,
                                                   const float* __restrict__ Wo,
                                                   const float* __restrict__ bi,
                                                   const float* __restrict__ bh,
                                                   const float* __restrict__ f_bonds,
                                                   const int* __restrict__ a2b,
                                                   unsigned short* __restrict__ Wi_f,
                                                   unsigned short* __restrict__ Wb_f,
                                                   unsigned short* __restrict__ Whm_f,
                                                   unsigned short* __restrict__ Woa_f,
                                                   unsigned short* __restrict__ Wom_f,
                                                   unsigned short* __restrict__ bondsum,
                                                   float* __restrict__ b_ih) {
    if (blockIdx.x < 256) {
        const int n = blockIdx.x;
        if (n == 0) b_ih[threadIdx.x] = bi[threadIdx.x] + bh[threadIdx.x];
        for (int k = threadIdx.x; k < KI; k += 256) {
            Wi_f[fidx(KI, n, k)]  = f2bf(k < AF ? Wi[k * HID + n] : 0.f);
            Woa_f[fidx(KI, n, k)] = f2bf(k < AF ? Wo[k * HID + n] : 0.f);
        }
        for (int k = threadIdx.x; k < KB; k += 256)
            Wb_f[fidx(KB, n, k)] = f2bf(k < 14 ? Wh[(HID + k) * HID + n] : 0.f);
        for (int k = threadIdx.x; k < KP; k += 256) {
            Whm_f[fidx(KP, n, k)] = f2bf(Wh[k * HID + n]);
            Wom_f[fidx(KP, n, k)] = f2bf(Wo[(AF + k) * HID + n]);
        }
    } else {
        const int id   = (blockIdx.x - 256) * 256 + threadIdx.x;
        const int atom = id >> 4;
        const int c    = id & 15;
        float s = 0.f;
        if (c < 14) {
            const int* nb = &a2b[atom * NNB];
#pragma unroll
            for (int t = 0; t < NNB; ++t)
                s += f_bonds[(size_t)nb[t] * BT + (BT - 14) + c];
        }
        bondsum[atom * 32 + c]      = f2bf(s);
        bondsum[atom * 32 + 16 + c] = 0;
    }
}

// ---------------------------------------------------------------------------
// MFMA core with B-panel register prefetch.
// cw = col-wave (0..7) owning cols cw*32 .. cw*32+31.
// ---------------------------------------------------------------------------
template<int K, int LS>
__device__ __forceinline__ void mfma_core_pf(const unsigned short* __restrict__ As,
                                             const unsigned short* __restrict__ Wt,
                                             f32x4 (&acc)[2][2], int cw, int lane) {
    constexpr int NK = K >> 5;
    const int lm = lane & 15, quad = lane >> 4;
    const short8* __restrict__ Wf = (const short8*)Wt;
    short8 bf[2][NK];
#pragma unroll
    for (int ks = 0; ks < NK; ++ks)
#pragma unroll
        for (int ct = 0; ct < 2; ++ct)
            bf[ct][ks] = Wf[(size_t)((cw * 2 + ct) * NK + ks) * 64 + lane];
#pragma unroll
    for (int ks = 0; ks < NK; ++ks) {
        short8 af[2];
#pragma unroll
        for (int rt = 0; rt < 2; ++rt)
            af[rt] = *(const short8*)&As[(rt * 16 + lm) * LS + ks * 32 + quad * 8];
#pragma unroll
        for (int rt = 0; rt < 2; ++rt)
#pragma unroll
            for (int ct = 0; ct < 2; ++ct)
                acc[rt][ct] = __builtin_amdgcn_mfma_f32_16x16x32_bf16(af[rt], bf[ct][ks], acc[rt][ct], 0, 0, 0);
    }
}

// C-layout acc -> bf16 tile in LDS (rows 0..31, stride LSP)
__device__ __forceinline__ void epi_to_lds(f32x4 (&acc)[2][2],
                                           const float* __restrict__ bias,
                                           bool relu_,
                                           unsigned short* __restrict__ E,
                                           int cw, int lane) {
    const int lm = lane & 15, quad = lane >> 4;
#pragma unroll
    for (int ct = 0; ct < 2; ++ct) {
        int col = cw * 32 + ct * 16 + lm;
        float bv = bias ? bias[col] : 0.f;
#pragma unroll
        for (int rt = 0; rt < 2; ++rt)
#pragma unroll
            for (int i = 0; i < 4; ++i) {
                float v = acc[rt][ct][i] + bv;
                if (relu_) v = fmaxf(v, 0.f);
                E[(rt * 16 + quad * 4 + i) * LSP + col] = f2bf(v);
            }
    }
}

// coalesced 16B row-major store of a BM x 256 LDS tile, NT threads
template<int NT>
__device__ __forceinline__ void store_tile(unsigned short* __restrict__ dst, int base,
                                           const unsigned short* __restrict__ E, int tid) {
#pragma unroll
    for (int k = 0; k < BM * HID / (8 * NT); ++k) {
        int j = k * NT + tid;
        int r = j >> 5, g = j & 31;
        *(short8*)&dst[(size_t)(base + r) * HID + g * 8] = *(const short8*)&E[r * LSP + g * 8];
    }
}

// ---------------------------------------------------------------------------
// k_inp (32-row tiles, 512 thr = 8 col-waves), 5 barriers — R8 best config:
// (512,8) -> 32 waves/CU, VGPR 32, 4 blocks x 36864 B LDS = 147.5 KB OK.
// ---------------------------------------------------------------------------
__global__ __launch_bounds__(512, 8) void k_inp(const float* __restrict__ atom,
                                                const unsigned short* __restrict__ bondsum,
                                                const unsigned short* __restrict__ Wi_f,
                                                const unsigned short* __restrict__ Wb_f,
                                                const unsigned short* __restrict__ Whm_f,
                                                const unsigned short* __restrict__ Woa_f,
                                                const float* __restrict__ bi,
                                                const float* __restrict__ b_ih,
                                                const float* __restrict__ bo,
                                                unsigned short* __restrict__ P0,
                                                unsigned short* __restrict__ inp2,
                                                unsigned short* __restrict__ aw) {
    // pool: X (BM*LSP: atomT then epi tile B) | work (BM*LSP) | bs (BM*LSB)
    __shared__ unsigned short pool[BM * LSP * 2 + BM * LSB];  // 36864 B
    unsigned short* X    = pool;
    unsigned short* work = pool + BM * LSP;
    unsigned short* bs   = pool + BM * LSP * 2;
    const int tid  = threadIdx.x;
    const int base = blockIdx.x * BM;

    for (int it = tid; it < BM * KI; it += 512) {
        int r = it / KI, c = it - r * KI;
        X[r * LSI + c] = f2bf(c < AF ? atom[(size_t)(base + r) * AF + c] : 0.f);
    }
    if (tid < BM * 4) {
        int r = tid >> 2, c = (tid & 3) * 8;
        *(short8*)&bs[r * LSB + c] = *(const short8*)&bondsum[(size_t)(base + r) * 32 + c];
    }
    __syncthreads();                                    // (1) staging visible

    const int lane = tid & 63, cw = tid >> 6;           // col-wave 0..7
    f32x4 acc1[2][2] = {}, acc3[2][2] = {};
    mfma_core_pf<KI, LSI>(X, Wi_f, acc1, cw, lane);     // inp tile
    mfma_core_pf<KI, LSI>(X, Woa_f, acc3, cw, lane);    // aw tile
    __syncthreads();                                    // (2) atomT reads done

    epi_to_lds(acc3, bo, false, X, cw, lane);           // aw tile (acc3 retires)
    epi_to_lds(acc1, bi, true, work, cw, lane);         // mT = relu(inp)
    __syncthreads();                                    // (3)

    store_tile<512>(aw, base, X, tid);                  // overlaps MFMAs below
    f32x4 acc2[2][2] = {};
    mfma_core_pf<KP, LSP>(work, Whm_f, acc2, cw, lane); // P0 = m @ Whm
    mfma_core_pf<KB, LSB>(bs, Wb_f, acc1, cw, lane);    // + bond part
    __syncthreads();                                    // (4) mT/X/bs reads done

    epi_to_lds(acc2, nullptr, false, X, cw, lane);
    epi_to_lds(acc1, b_ih, false, work, cw, lane);
    __syncthreads();                                    // (5)

    store_tile<512>(P0, base, X, tid);
    store_tile<512>(inp2, base, work, tid);
}

// ---------------------------------------------------------------------------
// k_it (fused gather+proj, 32-row tiles, 512 thr = 8 col-waves) — R8 form:
// nb_l LDS broadcast for indices (192 coalesced loads, not 3072).
//   m = relu(base_ + sum_t Pin[a2a[.,t]])  (LDS only);  Pout = m @ Wt
// ---------------------------------------------------------------------------
__global__ __launch_bounds__(512, 8) void k_it(const unsigned short* __restrict__ Pin,
                                               const unsigned short* __restrict__ base_,
                                               const int* __restrict__ a2a,
                                               const unsigned short* __restrict__ Wt,
                                               unsigned short* __restrict__ Pout) {
    __shared__ unsigned short mT[BM * LSP];
    __shared__ int nb_l[BM * NNB];
    const int tid  = threadIdx.x;
    const int base = blockIdx.x * BM;

    if (tid < BM * NNB) nb_l[tid] = a2a[base * NNB + tid];
    __syncthreads();

#pragma unroll
    for (int k = 0; k < 2; ++k) {
        int j = k * 512 + tid;
        int r = j >> 5, g = j & 31;
        const int* nb = &nb_l[r * NNB];
        float s[8] = {};
#pragma unroll
        for (int t = 0; t < NNB; ++t) {
            short8 u = *(const short8*)&Pin[(size_t)nb[t] * HID + g * 8];
#pragma unroll
            for (int q = 0; q < 8; ++q) s[q] += bf2f((unsigned short)u[q]);
        }
        short8 b = *(const short8*)&base_[(size_t)(base + r) * HID + g * 8];
        short8 o;
#pragma unroll
        for (int q = 0; q < 8; ++q)
            o[q] = (short)f2bf(fmaxf(s[q] + bf2f((unsigned short)b[q]), 0.f));
        *(short8*)&mT[r * LSP + g * 8] = o;
    }
    __syncthreads();

    const int lane = tid & 63, cw = tid >> 6;
    f32x4 acc[2][2] = {};
    mfma_core_pf<KP, LSP>(mT, Wt, acc, cw, lane);
    __syncthreads();
    epi_to_lds(acc, nullptr, false, mT, cw, lane);
    __syncthreads();
    store_tile<512>(Pout, base, mT, tid);
}

// ---------------------------------------------------------------------------
// k_gseg (fused final gather + segment mean): one block per molecule.
// (256,8): 32 waves/CU; gather loop unroll 2.
// ---------------------------------------------------------------------------
__global__ __launch_bounds__(256, 8) void k_gseg(const unsigned short* __restrict__ P,
                                                 const unsigned short* __restrict__ aw,
                                                 const int* __restrict__ a2a,
                                                 const int* __restrict__ seg,
                                                 float* __restrict__ out) {
    const int m = blockIdx.x;
    __shared__ int lohi[2];
    __shared__ float red[8 * 256];   // 8 KB
    if (threadIdx.x == 0) {
        int lo = 0, hi = N_ATOMS;
        while (lo < hi) { int mid = (lo + hi) >> 1; if (seg[mid] < m) lo = mid + 1; else hi = mid; }
        lohi[0] = lo;
        int lo2 = lo, hi2 = N_ATOMS;
        while (lo2 < hi2) { int mid = (lo2 + hi2) >> 1; if (seg[mid] < m + 1) lo2 = mid + 1; else hi2 = mid; }
        lohi[1] = lo2;
    }
    __syncthreads();
    const int lo = lohi[0], hi = lohi[1];
    const int slot = threadIdx.x >> 5;    // 0..7 (row slot)
    const int cg   = threadIdx.x & 31;    // 0..31 (8-channel group)

    float s[8] = {};
#pragma unroll 2
    for (int i0 = lo; i0 < hi; i0 += 8) {
        int i = i0 + slot;
        if (i < hi) {
            const int* nb = &a2a[i * NNB];
            short8 a = *(const short8*)&aw[(size_t)i * HID + cg * 8];
            float v[8];
#pragma unroll
            for (int q = 0; q < 8; ++q) v[q] = bf2f((unsigned short)a[q]);
#pragma unroll
            for (int t = 0; t < NNB; ++t) {
                short8 u = *(const short8*)&P[(size_t)nb[t] * HID + cg * 8];
#pragma unroll
                for (int q = 0; q < 8; ++q) v[q] += bf2f((unsigned short)u[q]);
            }
#pragma unroll
            for (int q = 0; q < 8; ++q) s[q] += fmaxf(v[q], 0.f);
        }
    }
#pragma unroll
    for (int q = 0; q < 8; ++q) red[slot * 256 + cg * 8 + q] = s[q];
    __syncthreads();

    const int j = threadIdx.x;
    float tot = 0.f;
#pragma unroll
    for (int sl = 0; sl < 8; ++sl) tot += red[sl * 256 + j];
    const int cnt = hi - lo;
    out[m * HID + j] = (cnt > 0) ? (tot / (float)cnt) : 0.f;
}

// ---------------------------------------------------------------------------
extern "C" void kernel_launch(void* const* d_in, const int* in_sizes, int n_in,
                              void* d_out, int out_size, void* d_ws, size_t ws_size,
                              hipStream_t stream) {
    const float* atom    = (const float*)d_in[0];
    const float* f_bonds = (const float*)d_in[1];
    const int*   a2a     = (const int*)d_in[2];
    const int*   a2b     = (const int*)d_in[3];
    const int*   seg     = (const int*)d_in[4];
    const float* Wi      = (const float*)d_in[5];
    const float* bi      = (const float*)d_in[6];
    const float* Wh      = (const float*)d_in[7];
    const float* bh      = (const float*)d_in[8];
    const float* Wo      = (const float*)d_in[9];
    const float* bo      = (const float*)d_in[10];
    float* out = (float*)d_out;

    unsigned short* ws = (unsigned short*)d_ws;
    const size_t nh = (size_t)N_ATOMS * HID;
    unsigned short* Pa   = ws;               // 32 MB
    unsigned short* Pb   = Pa + nh;          // 32 MB
    unsigned short* inp2 = Pb + nh;          // 32 MB
    unsigned short* aw   = inp2 + nh;        // 32 MB
    unsigned short* bsum = aw + nh;          // 4 MB
    unsigned short* Wi_f  = bsum + (size_t)N_ATOMS * 32;
    unsigned short* Wb_f  = Wi_f + 256 * KI;
    unsigned short* Whm_f = Wb_f + 256 * KB;
    unsigned short* Woa_f = Whm_f + 256 * KP;
    unsigned short* Wom_f = Woa_f + 256 * KI;
    float*          b_ih  = (float*)(Wom_f + 256 * KP);

    dim3 blk256(256), blk512(512);
    const int nbm = N_ATOMS / BM;   // 2048

    k_prep_bond<<<256 + N_ATOMS * 16 / 256, blk256, 0, stream>>>(
        Wi, Wh, Wo, bi, bh, f_bonds, a2b,
        Wi_f, Wb_f, Whm_f, Woa_f, Wom_f, bsum, b_ih);
    k_inp<<<nbm, blk512, 0, stream>>>(atom, bsum, Wi_f, Wb_f, Whm_f, Woa_f,
                                      bi, b_ih, bo, Pa, inp2, aw);

    k_it<<<nbm, blk512, 0, stream>>>(Pa, inp2, a2a, Whm_f, Pb);   // -> P1
    k_it<<<nbm, blk512, 0, stream>>>(Pb, inp2, a2a, Wom_f, Pa);   // -> P2
    k_gseg<<<NM, blk256, 0, stream>>>(Pa, aw, a2a, seg, out);
}

// Round 11
// 311.523 us; speedup vs baseline: 1.1882x; 1.1228x over previous
//
#include <hip/hip_runtime.h>

#define N_ATOMS 65536
#define AF      133
#define BT      147
#define HID     256
#define NNB     6
#define NM      2048

#define KI   160        // atom(133) padded
#define KB   32         // bond(14) padded
#define KP   256        // msg-side GEMMs (exact)
// LDS strides (elements)
#define LSI  168
#define LSB  40
#define LSP  264        // MUST stay a multiple of 8 elements (16 B): R10's 268
                        // broke b128 alignment on odd rows (-26% k_inp).

#define BM   32         // rows per block; 8 col-waves of 32 cols each (R8 best)

typedef __attribute__((ext_vector_type(8))) short short8;
typedef __attribute__((ext_vector_type(4))) float f32x4;

__device__ __forceinline__ unsigned short f2bf(float f) {
    unsigned u = __builtin_bit_cast(unsigned, f);
    u += 0x7fffu + ((u >> 16) & 1u);
    return (unsigned short)(u >> 16);
}
__device__ __forceinline__ float bf2f(unsigned short s) {
    unsigned u = ((unsigned)s) << 16;
    return __builtin_bit_cast(float, u);
}

// ---------------------------------------------------------------------------
// Fragment-order index for a [256 x K] W^T (bf16) in MFMA B-fragment order.
// ---------------------------------------------------------------------------
__device__ __forceinline__ size_t fidx(int K, int n, int k) {
    return ((size_t)(((n >> 4) * (K >> 5) + (k >> 5)) * 64
                     + (((k >> 3) & 3) << 4) + (n & 15)) << 3) + (k & 7);
}

// ---------------------------------------------------------------------------
// k_prep_bond: weight transposes -> FRAGMENT ORDER (bf16) + b_ih + bondsum.
// (standalone bond gather: folding into k_inp failed in R6 — VMEM retires
//  in order, slow gathers poison later vmcnt waits.)
// ---------------------------------------------------------------------------
__global__ __launch_bounds__(256) void k_prep_bond(const float* __restrict__ Wi,
                                                   const float* __restrict__ Wh,
                                                   const float* __restrict__ Wo,
                                                   const float* __restrict__ bi,
                                                   const float* __restrict__ bh,
                                                   const float* __restrict__ f_bonds,
                                                   const int* __restrict__ a2b,
                                                   unsigned short* __restrict__ Wi_f,
                                                   unsigned short* __restrict__ Wb_f,
                                                   unsigned short* __restrict__ Whm_f,
                                                   unsigned short* __restrict__ Woa_f,
                                                   unsigned short* __restrict__ Wom_f,
                                                   unsigned short* __restrict__ bondsum,
                                                   float* __restrict__ b_ih) {
    if (blockIdx.x < 256) {
        const int n = blockIdx.x;
        if (n == 0) b_ih[threadIdx.x] = bi[threadIdx.x] + bh[threadIdx.x];
        for (int k = threadIdx.x; k < KI; k += 256) {
            Wi_f[fidx(KI, n, k)]  = f2bf(k < AF ? Wi[k * HID + n] : 0.f);
            Woa_f[fidx(KI, n, k)] = f2bf(k < AF ? Wo[k * HID + n] : 0.f);
        }
        for (int k = threadIdx.x; k < KB; k += 256)
            Wb_f[fidx(KB, n, k)] = f2bf(k < 14 ? Wh[(HID + k) * HID + n] : 0.f);
        for (int k = threadIdx.x; k < KP; k += 256) {
            Whm_f[fidx(KP, n, k)] = f2bf(Wh[k * HID + n]);
            Wom_f[fidx(KP, n, k)] = f2bf(Wo[(AF + k) * HID + n]);
        }
    } else {
        const int id   = (blockIdx.x - 256) * 256 + threadIdx.x;
        const int atom = id >> 4;
        const int c    = id & 15;
        float s = 0.f;
        if (c < 14) {
            const int* nb = &a2b[atom * NNB];
#pragma unroll
            for (int t = 0; t < NNB; ++t)
                s += f_bonds[(size_t)nb[t] * BT + (BT - 14) + c];
        }
        bondsum[atom * 32 + c]      = f2bf(s);
        bondsum[atom * 32 + 16 + c] = 0;
    }
}

// ---------------------------------------------------------------------------
// MFMA core with B-panel register prefetch.
// cw = col-wave (0..7) owning cols cw*32 .. cw*32+31.
// ---------------------------------------------------------------------------
template<int K, int LS>
__device__ __forceinline__ void mfma_core_pf(const unsigned short* __restrict__ As,
                                             const unsigned short* __restrict__ Wt,
                                             f32x4 (&acc)[2][2], int cw, int lane) {
    constexpr int NK = K >> 5;
    const int lm = lane & 15, quad = lane >> 4;
    const short8* __restrict__ Wf = (const short8*)Wt;
    short8 bf[2][NK];
#pragma unroll
    for (int ks = 0; ks < NK; ++ks)
#pragma unroll
        for (int ct = 0; ct < 2; ++ct)
            bf[ct][ks] = Wf[(size_t)((cw * 2 + ct) * NK + ks) * 64 + lane];
#pragma unroll
    for (int ks = 0; ks < NK; ++ks) {
        short8 af[2];
#pragma unroll
        for (int rt = 0; rt < 2; ++rt)
            af[rt] = *(const short8*)&As[(rt * 16 + lm) * LS + ks * 32 + quad * 8];
#pragma unroll
        for (int rt = 0; rt < 2; ++rt)
#pragma unroll
            for (int ct = 0; ct < 2; ++ct)
                acc[rt][ct] = __builtin_amdgcn_mfma_f32_16x16x32_bf16(af[rt], bf[ct][ks], acc[rt][ct], 0, 0, 0);
    }
}

// C-layout acc -> bf16 tile in LDS (rows 0..31, stride LSP)
__device__ __forceinline__ void epi_to_lds(f32x4 (&acc)[2][2],
                                           const float* __restrict__ bias,
                                           bool relu_,
                                           unsigned short* __restrict__ E,
                                           int cw, int lane) {
    const int lm = lane & 15, quad = lane >> 4;
#pragma unroll
    for (int ct = 0; ct < 2; ++ct) {
        int col = cw * 32 + ct * 16 + lm;
        float bv = bias ? bias[col] : 0.f;
#pragma unroll
        for (int rt = 0; rt < 2; ++rt)
#pragma unroll
            for (int i = 0; i < 4; ++i) {
                float v = acc[rt][ct][i] + bv;
                if (relu_) v = fmaxf(v, 0.f);
                E[(rt * 16 + quad * 4 + i) * LSP + col] = f2bf(v);
            }
    }
}

// coalesced 16B row-major store of a BM x 256 LDS tile, NT threads
template<int NT>
__device__ __forceinline__ void store_tile(unsigned short* __restrict__ dst, int base,
                                           const unsigned short* __restrict__ E, int tid) {
#pragma unroll
    for (int k = 0; k < BM * HID / (8 * NT); ++k) {
        int j = k * NT + tid;
        int r = j >> 5, g = j & 31;
        *(short8*)&dst[(size_t)(base + r) * HID + g * 8] = *(const short8*)&E[r * LSP + g * 8];
    }
}

// ---------------------------------------------------------------------------
// k_inp (32-row tiles, 512 thr = 8 col-waves), 5 barriers — R8 best config:
// (512,8) -> 32 waves/CU, VGPR 32, 4 blocks x 36352 B LDS = 145.4 KB OK.
// ---------------------------------------------------------------------------
__global__ __launch_bounds__(512, 8) void k_inp(const float* __restrict__ atom,
                                                const unsigned short* __restrict__ bondsum,
                                                const unsigned short* __restrict__ Wi_f,
                                                const unsigned short* __restrict__ Wb_f,
                                                const unsigned short* __restrict__ Whm_f,
                                                const unsigned short* __restrict__ Woa_f,
                                                const float* __restrict__ bi,
                                                const float* __restrict__ b_ih,
                                                const float* __restrict__ bo,
                                                unsigned short* __restrict__ P0,
                                                unsigned short* __restrict__ inp2,
                                                unsigned short* __restrict__ aw) {
    // pool: X (BM*LSP: atomT then epi tile B) | work (BM*LSP) | bs (BM*LSB)
    __shared__ unsigned short pool[BM * LSP * 2 + BM * LSB];  // 36352 B
    unsigned short* X    = pool;
    unsigned short* work = pool + BM * LSP;
    unsigned short* bs   = pool + BM * LSP * 2;
    const int tid  = threadIdx.x;
    const int base = blockIdx.x * BM;

    for (int it = tid; it < BM * KI; it += 512) {
        int r = it / KI, c = it - r * KI;
        X[r * LSI + c] = f2bf(c < AF ? atom[(size_t)(base + r) * AF + c] : 0.f);
    }
    if (tid < BM * 4) {
        int r = tid >> 2, c = (tid & 3) * 8;
        *(short8*)&bs[r * LSB + c] = *(const short8*)&bondsum[(size_t)(base + r) * 32 + c];
    }
    __syncthreads();                                    // (1) staging visible

    const int lane = tid & 63, cw = tid >> 6;           // col-wave 0..7
    f32x4 acc1[2][2] = {}, acc3[2][2] = {};
    mfma_core_pf<KI, LSI>(X, Wi_f, acc1, cw, lane);     // inp tile
    mfma_core_pf<KI, LSI>(X, Woa_f, acc3, cw, lane);    // aw tile
    __syncthreads();                                    // (2) atomT reads done

    epi_to_lds(acc3, bo, false, X, cw, lane);           // aw tile (acc3 retires)
    epi_to_lds(acc1, bi, true, work, cw, lane);         // mT = relu(inp)
    __syncthreads();                                    // (3)

    store_tile<512>(aw, base, X, tid);                  // overlaps MFMAs below
    f32x4 acc2[2][2] = {};
    mfma_core_pf<KP, LSP>(work, Whm_f, acc2, cw, lane); // P0 = m @ Whm
    mfma_core_pf<KB, LSB>(bs, Wb_f, acc1, cw, lane);    // + bond part
    __syncthreads();                                    // (4) mT/X/bs reads done

    epi_to_lds(acc2, nullptr, false, X, cw, lane);
    epi_to_lds(acc1, b_ih, false, work, cw, lane);
    __syncthreads();                                    // (5)

    store_tile<512>(P0, base, X, tid);
    store_tile<512>(inp2, base, work, tid);
}

// ---------------------------------------------------------------------------
// k_it (fused gather+proj, 32-row tiles, 512 thr = 8 col-waves) — R8 form:
// nb_l LDS broadcast for indices (192 coalesced loads, not 3072).
//   m = relu(base_ + sum_t Pin[a2a[.,t]])  (LDS only);  Pout = m @ Wt
// ---------------------------------------------------------------------------
__global__ __launch_bounds__(512, 8) void k_it(const unsigned short* __restrict__ Pin,
                                               const unsigned short* __restrict__ base_,
                                               const int* __restrict__ a2a,
                                               const unsigned short* __restrict__ Wt,
                                               unsigned short* __restrict__ Pout) {
    __shared__ unsigned short mT[BM * LSP];
    __shared__ int nb_l[BM * NNB];
    const int tid  = threadIdx.x;
    const int base = blockIdx.x * BM;

    if (tid < BM * NNB) nb_l[tid] = a2a[base * NNB + tid];
    __syncthreads();

#pragma unroll
    for (int k = 0; k < 2; ++k) {
        int j = k * 512 + tid;
        int r = j >> 5, g = j & 31;
        const int* nb = &nb_l[r * NNB];
        float s[8] = {};
#pragma unroll
        for (int t = 0; t < NNB; ++t) {
            short8 u = *(const short8*)&Pin[(size_t)nb[t] * HID + g * 8];
#pragma unroll
            for (int q = 0; q < 8; ++q) s[q] += bf2f((unsigned short)u[q]);
        }
        short8 b = *(const short8*)&base_[(size_t)(base + r) * HID + g * 8];
        short8 o;
#pragma unroll
        for (int q = 0; q < 8; ++q)
            o[q] = (short)f2bf(fmaxf(s[q] + bf2f((unsigned short)b[q]), 0.f));
        *(short8*)&mT[r * LSP + g * 8] = o;
    }
    __syncthreads();

    const int lane = tid & 63, cw = tid >> 6;
    f32x4 acc[2][2] = {};
    mfma_core_pf<KP, LSP>(mT, Wt, acc, cw, lane);
    __syncthreads();
    epi_to_lds(acc, nullptr, false, mT, cw, lane);
    __syncthreads();
    store_tile<512>(Pout, base, mT, tid);
}

// ---------------------------------------------------------------------------
// k_gseg (fused final gather + segment mean): one block per molecule.
// (256,8): 32 waves/CU; gather loop unroll 2.
// ---------------------------------------------------------------------------
__global__ __launch_bounds__(256, 8) void k_gseg(const unsigned short* __restrict__ P,
                                                 const unsigned short* __restrict__ aw,
                                                 const int* __restrict__ a2a,
                                                 const int* __restrict__ seg,
                                                 float* __restrict__ out) {
    const int m = blockIdx.x;
    __shared__ int lohi[2];
    __shared__ float red[8 * 256];   // 8 KB
    if (threadIdx.x == 0) {
        int lo = 0, hi = N_ATOMS;
        while (lo < hi) { int mid = (lo + hi) >> 1; if (seg[mid] < m) lo = mid + 1; else hi = mid; }
        lohi[0] = lo;
        int lo2 = lo, hi2 = N_ATOMS;
        while (lo2 < hi2) { int mid = (lo2 + hi2) >> 1; if (seg[mid] < m + 1) lo2 = mid + 1; else hi2 = mid; }
        lohi[1] = lo2;
    }
    __syncthreads();
    const int lo = lohi[0], hi = lohi[1];
    const int slot = threadIdx.x >> 5;    // 0..7 (row slot)
    const int cg   = threadIdx.x & 31;    // 0..31 (8-channel group)

    float s[8] = {};
#pragma unroll 2
    for (int i0 = lo; i0 < hi; i0 += 8) {
        int i = i0 + slot;
        if (i < hi) {
            const int* nb = &a2a[i * NNB];
            short8 a = *(const short8*)&aw[(size_t)i * HID + cg * 8];
            float v[8];
#pragma unroll
            for (int q = 0; q < 8; ++q) v[q] = bf2f((unsigned short)a[q]);
#pragma unroll
            for (int t = 0; t < NNB; ++t) {
                short8 u = *(const short8*)&P[(size_t)nb[t] * HID + cg * 8];
#pragma unroll
                for (int q = 0; q < 8; ++q) v[q] += bf2f((unsigned short)u[q]);
            }
#pragma unroll
            for (int q = 0; q < 8; ++q) s[q] += fmaxf(v[q], 0.f);
        }
    }
#pragma unroll
    for (int q = 0; q < 8; ++q) red[slot * 256 + cg * 8 + q] = s[q];
    __syncthreads();

    const int j = threadIdx.x;
    float tot = 0.f;
#pragma unroll
    for (int sl = 0; sl < 8; ++sl) tot += red[sl * 256 + j];
    const int cnt = hi - lo;
    out[m * HID + j] = (cnt > 0) ? (tot / (float)cnt) : 0.f;
}

// ---------------------------------------------------------------------------
extern "C" void kernel_launch(void* const* d_in, const int* in_sizes, int n_in,
                              void* d_out, int out_size, void* d_ws, size_t ws_size,
                              hipStream_t stream) {
    const float* atom    = (const float*)d_in[0];
    const float* f_bonds = (const float*)d_in[1];
    const int*   a2a     = (const int*)d_in[2];
    const int*   a2b     = (const int*)d_in[3];
    const int*   seg     = (const int*)d_in[4];
    const float* Wi      = (const float*)d_in[5];
    const float* bi      = (const float*)d_in[6];
    const float* Wh      = (const float*)d_in[7];
    const float* bh      = (const float*)d_in[8];
    const float* Wo      = (const float*)d_in[9];
    const float* bo      = (const float*)d_in[10];
    float* out = (float*)d_out;

    unsigned short* ws = (unsigned short*)d_ws;
    const size_t nh = (size_t)N_ATOMS * HID;
    unsigned short* Pa   = ws;               // 32 MB
    unsigned short* Pb   = Pa + nh;          // 32 MB
    unsigned short* inp2 = Pb + nh;          // 32 MB
    unsigned short* aw   = inp2 + nh;        // 32 MB
    unsigned short* bsum = aw + nh;          // 4 MB
    unsigned short* Wi_f  = bsum + (size_t)N_ATOMS * 32;
    unsigned short* Wb_f  = Wi_f + 256 * KI;
    unsigned short* Whm_f = Wb_f + 256 * KB;
    unsigned short* Woa_f = Whm_f + 256 * KP;
    unsigned short* Wom_f = Woa_f + 256 * KI;
    float*          b_ih  = (float*)(Wom_f + 256 * KP);

    dim3 blk256(256), blk512(512);
    const int nbm = N_ATOMS / BM;   // 2048

    k_prep_bond<<<256 + N_ATOMS * 16 / 256, blk256, 0, stream>>>(
        Wi, Wh, Wo, bi, bh, f_bonds, a2b,
        Wi_f, Wb_f, Whm_f, Woa_f, Wom_f, bsum, b_ih);
    k_inp<<<nbm, blk512, 0, stream>>>(atom, bsum, Wi_f, Wb_f, Whm_f, Woa_f,
                                      bi, b_ih, bo, Pa, inp2, aw);

    k_it<<<nbm, blk512, 0, stream>>>(Pa, inp2, a2a, Whm_f, Pb);   // -> P1
    k_it<<<nbm, blk512, 0, stream>>>(Pb, inp2, a2a, Wom_f, Pa);   // -> P2
    k_gseg<<<NM, blk256, 0, stream>>>(Pa, aw, a2a, seg, out);
}